// Round 7
// baseline (35.251 us; speedup 1.0000x reference)
//
#include <hip/hip_runtime.h>
#include <hip/hip_bf16.h>
#include <math.h>

#define KN 8192
#define DEG 32
#define EE (KN*DEG)

// VAR = float32(10^(-19.9) * 5000000 / 10)
#define VAR_F 6.294627058970831e-15f

typedef __attribute__((ext_vector_type(8)))  short bf16x8;
typedef __attribute__((ext_vector_type(16))) float f32x16;

static __device__ __forceinline__ short bf_hi(float f) {
    __hip_bfloat16 h = __float2bfloat16(f);
    return __builtin_bit_cast(short, h);
}
static __device__ __forceinline__ float bf_f(short s) {
    __hip_bfloat16 h = __builtin_bit_cast(__hip_bfloat16, s);
    return __bfloat162float(h);
}

// Raw (fp32) per-node register buffer: everything one node needs from HBM.
struct RawW {
    float a_e;
    float wm1[9];
    float w9v[16];
    float wm2f[16];
    float bm1_i, bm2_i;
    float wu1[11];
    float bu1_m, wu2a, wu2b, bu2_o;
    float wh1[8];
    float bh1_m, wh2_m, bh2_k;
    float x9;
    float Hv, Hdiag;
    int   dv;
};

// Kernel 1: fused 3x conv + head + H-row gather. One wave per block; each
// wave processes 4 consecutive nodes with depth-1 register prefetch
// (L0,L1,C0,L2,C1,L3,C2,C3): node n+1's ~9.5KB weight stream overlaps node
// n's compute, keeping HBM busy continuously. Grid = 2048 blocks = exactly
// 8 blocks/CU resident (VGPR budget 256 via __launch_bounds__(64,2)).
// msg GEMM via mfma_f32_32x32x16_bf16, 3-term hi/lo split (~fp32 precision).
// All LDS wave-private -> no barriers.
__global__ __launch_bounds__(64, 2) void mpnn_fused(
    const float* __restrict__ x,
    const float* __restrict__ edge_attr,
    const float* __restrict__ H,
    const int* __restrict__ edge_index,
    const float* __restrict__ Wm1, const float* __restrict__ bm1,
    const float* __restrict__ Wm2, const float* __restrict__ bm2,
    const float* __restrict__ Wu1, const float* __restrict__ bu1,
    const float* __restrict__ Wu2, const float* __restrict__ bu2,
    const float* __restrict__ Wh1, const float* __restrict__ bh1,
    const float* __restrict__ Wh2, const float* __restrict__ bh2,
    float* __restrict__ p_ws, float* __restrict__ valid_ws,
    float* __restrict__ hv_ws)
{
    __shared__ __align__(16) float c_lds[32];
    __shared__ float xt[44];    // [0..8]=x, [9..40]=aggr
    __shared__ float ubuf[16];

    const int lane = threadIdx.x;
    const int col  = lane & 31;
    const int g    = lane >> 5;
    const int m    = lane & 15;
    const int dg   = lane >> 4;      // 0..3
    const int o    = lane & 7;
    const int mg   = lane >> 3;      // 0..7

    const int* dstp = edge_index + EE;

    auto load_raw = [&](RawW& r, int k) {
        r.dv  = dstp[k*DEG + col];                 // FIRST: longest dep chain
        r.a_e = edge_attr[k*32 + col];

        #pragma unroll
        for (int d = 0; d < 9; ++d) r.wm1[d] = Wm1[(size_t)k*320 + d*32 + col];

        {   // Wm1 row 9 in A-fragment order: j = s*16 + g*8 + i
            const float* w9p = Wm1 + (size_t)k*320 + 288;
            float4 wa = *(const float4*)(w9p + g*8);
            float4 wb = *(const float4*)(w9p + g*8 + 4);
            float4 wc = *(const float4*)(w9p + 16 + g*8);
            float4 wd = *(const float4*)(w9p + 16 + g*8 + 4);
            r.w9v[0]=wa.x;  r.w9v[1]=wa.y;  r.w9v[2]=wa.z;  r.w9v[3]=wa.w;
            r.w9v[4]=wb.x;  r.w9v[5]=wb.y;  r.w9v[6]=wb.z;  r.w9v[7]=wb.w;
            r.w9v[8]=wc.x;  r.w9v[9]=wc.y;  r.w9v[10]=wc.z; r.w9v[11]=wc.w;
            r.w9v[12]=wd.x; r.w9v[13]=wd.y; r.w9v[14]=wd.z; r.w9v[15]=wd.w;
        }

        // Wm2 in B-fragment order (2 coalesced 128B rows per instr)
        #pragma unroll
        for (int s = 0; s < 2; ++s)
            #pragma unroll
            for (int i = 0; i < 8; ++i)
                r.wm2f[s*8+i] = Wm2[(size_t)k*1024 + (s*16 + g*8 + i)*32 + col];

        r.bm1_i = bm1[k*32 + col];
        r.bm2_i = bm2[k*32 + col];

        #pragma unroll
        for (int t = 0; t < 11; ++t) {
            int d = dg*11 + t;
            r.wu1[t] = (d < 41) ? Wu1[(size_t)k*656 + d*16 + m] : 0.f;
        }
        r.bu1_m = bu1[k*16 + m];

        r.wu2a  = Wu2[(size_t)k*128 + (mg*2+0)*8 + o];
        r.wu2b  = Wu2[(size_t)k*128 + (mg*2+1)*8 + o];
        r.bu2_o = bu2[k*8 + o];

        #pragma unroll
        for (int d = 0; d < 8; ++d) r.wh1[d] = Wh1[(size_t)k*128 + d*16 + m];
        r.bh1_m = bh1[k*16 + m];
        r.wh2_m = Wh2[k*16 + m];
        r.bh2_k = bh2[k];

        r.x9 = x[(size_t)k*9 + (lane < 9 ? lane : 0)];

        r.Hdiag = H[(size_t)k*KN + k];
        r.Hv    = H[(size_t)k*KN + r.dv];   // LAST: its wait only drains
                                            // older (already-needed) loads
    };

    auto compute_node = [&](RawW& r, int k) {
        if (lane < 9) xt[lane] = r.x9;

        // B-fragment bf16 hi/lo conversion
        bf16x8 Bhi[2], Blo[2];
        #pragma unroll
        for (int s = 0; s < 2; ++s) {
            #pragma unroll
            for (int i = 0; i < 8; ++i) {
                float wv = r.wm2f[s*8+i];
                short h = bf_hi(wv);
                Bhi[s][i] = h;
                Blo[s][i] = bf_hi(wv - bf_f(h));
            }
        }

        for (int it = 0; it < 3; ++it) {
            // c_j = bm1_j + sum_d x_d Wm1[d][j]  (lane computes j = col)
            float c = r.bm1_i;
            #pragma unroll
            for (int d = 0; d < 9; ++d) c = fmaf(xt[d], r.wm1[d], c);
            if (g == 0) c_lds[col] = c;

            // A frags: A[e=col][kk=s*16+g*8+i] = relu(c_j + a_e*Wm1[9][j])
            const float4* cb = (const float4*)c_lds;
            float4 q0 = cb[g*2 + 0];
            float4 q1 = cb[g*2 + 1];
            float4 q2 = cb[4 + g*2 + 0];
            float4 q3 = cb[4 + g*2 + 1];
            float cv[16] = {q0.x,q0.y,q0.z,q0.w, q1.x,q1.y,q1.z,q1.w,
                            q2.x,q2.y,q2.z,q2.w, q3.x,q3.y,q3.z,q3.w};
            bf16x8 Ahi[2], Alo[2];
            #pragma unroll
            for (int s = 0; s < 2; ++s) {
                #pragma unroll
                for (int i = 0; i < 8; ++i) {
                    int t = s*8 + i;
                    float hv = fmaxf(fmaf(r.a_e, r.w9v[t], cv[t]), 0.f);
                    short h = bf_hi(hv);
                    Ahi[s][i] = h;
                    Alo[s][i] = bf_hi(hv - bf_f(h));
                }
            }

            // msg GEMM: D[e][i] = sum_j h[e][j] Wm2[j][i]
            f32x16 acc;
            #pragma unroll
            for (int rr = 0; rr < 16; ++rr) acc[rr] = 0.f;
            #pragma unroll
            for (int s = 0; s < 2; ++s) {
                acc = __builtin_amdgcn_mfma_f32_32x32x16_bf16(Ahi[s], Bhi[s], acc, 0, 0, 0);
                acc = __builtin_amdgcn_mfma_f32_32x32x16_bf16(Ahi[s], Blo[s], acc, 0, 0, 0);
                acc = __builtin_amdgcn_mfma_f32_32x32x16_bf16(Alo[s], Bhi[s], acc, 0, 0, 0);
            }

            // aggr_i = sum_e relu(bm2_i + D[e][i])
            float ag = 0.f;
            #pragma unroll
            for (int rr = 0; rr < 16; ++rr) ag += fmaxf(acc[rr] + r.bm2_i, 0.f);
            ag += __shfl_xor(ag, 32);
            if (g == 0) xt[9 + col] = ag;

            // u_m = relu(bu1_m + sum_{d<41} t_d Wu1[d][m])
            float up = 0.f;
            #pragma unroll
            for (int t = 0; t < 11; ++t) {
                int d = dg*11 + t;
                if (d < 41) up = fmaf(xt[d], r.wu1[t], up);
            }
            up += __shfl_xor(up, 16);
            up += __shfl_xor(up, 32);
            float u = fmaxf(up + r.bu1_m, 0.f);
            if (lane < 16) ubuf[lane] = u;

            // comb_o = relu(bu2_o + sum_m u_m Wu2[m][o])
            float cp = r.wu2a * ubuf[mg*2] + r.wu2b * ubuf[mg*2 + 1];
            cp += __shfl_xor(cp, 8);
            cp += __shfl_xor(cp, 16);
            cp += __shfl_xor(cp, 32);
            float comb = fmaxf(cp + r.bu2_o, 0.f);
            if (lane < 8) xt[1 + lane] = comb;   // x_new = [x0, comb]
        }

        // head
        float hp = 0.f;
        #pragma unroll
        for (int d = 0; d < 8; ++d) hp = fmaf(xt[1 + d], r.wh1[d], hp);
        float hh = fmaxf(hp + r.bh1_m, 0.f);
        float pp = hh * r.wh2_m;
        pp += __shfl_xor(pp, 1);
        pp += __shfl_xor(pp, 2);
        pp += __shfl_xor(pp, 4);
        pp += __shfl_xor(pp, 8);
        float z = pp + r.bh2_k;
        float p = 1.f / (1.f + expf(-z));

        if (g == 0) hv_ws[k*DEG + col] = r.Hv;
        if (lane == 0) {
            p_ws[k] = p;
            valid_ws[k] = p * r.Hdiag;
        }
    };

    const int k0 = blockIdx.x * 4;
    RawW A, B;
    load_raw(A, k0 + 0);
    load_raw(B, k0 + 1);
    compute_node(A, k0 + 0);
    load_raw(A, k0 + 2);
    compute_node(B, k0 + 1);
    load_raw(B, k0 + 3);
    compute_node(A, k0 + 2);
    compute_node(B, k0 + 3);
}

// Kernel 2b: interference reduce from compact buffers. 32 lanes per node.
// Streams hv_ws (1 MB) + dst (1 MB); p gather is a 32 KB L2-resident table.
__global__ __launch_bounds__(256) void mpnn_interf(
    const int* __restrict__ edge_index,
    const float* __restrict__ p_ws,
    const float* __restrict__ valid_ws,
    const float* __restrict__ hv_ws,
    float* __restrict__ out)
{
    const int t = blockIdx.x * 256 + threadIdx.x;
    const int s = t >> 5;
    const int e = t & 31;
    const int* dst = edge_index + EE;
    const int d = dst[s*DEG + e];
    float part = p_ws[d] * hv_ws[s*DEG + e];
    part += __shfl_xor(part, 1);
    part += __shfl_xor(part, 2);
    part += __shfl_xor(part, 4);
    part += __shfl_xor(part, 8);
    part += __shfl_xor(part, 16);
    if (e == 0) {
        float interf = part + VAR_F;
        out[s] = -log1pf(valid_ws[s] / interf) * 1.4426950408889634f;
    }
}

extern "C" void kernel_launch(void* const* d_in, const int* in_sizes, int n_in,
                              void* d_out, int out_size, void* d_ws, size_t ws_size,
                              hipStream_t stream) {
    const float* x         = (const float*)d_in[0];
    const float* edge_attr = (const float*)d_in[1];
    const float* H         = (const float*)d_in[2];
    const int*   edge_idx  = (const int*)  d_in[3];
    const float* Wm1 = (const float*)d_in[4];
    const float* bm1 = (const float*)d_in[5];
    const float* Wm2 = (const float*)d_in[6];
    const float* bm2 = (const float*)d_in[7];
    const float* Wu1 = (const float*)d_in[8];
    const float* bu1 = (const float*)d_in[9];
    const float* Wu2 = (const float*)d_in[10];
    const float* bu2 = (const float*)d_in[11];
    const float* Wh1 = (const float*)d_in[12];
    const float* bh1 = (const float*)d_in[13];
    const float* Wh2 = (const float*)d_in[14];
    const float* bh2 = (const float*)d_in[15];
    float* out = (float*)d_out;

    float* p_ws     = (float*)d_ws;            // KN
    float* valid_ws = p_ws + KN;               // KN
    float* hv_ws    = valid_ws + KN;           // KN*DEG

    mpnn_fused<<<KN/4, 64, 0, stream>>>(x, edge_attr, H, edge_idx,
                                        Wm1, bm1, Wm2, bm2,
                                        Wu1, bu1, Wu2, bu2, Wh1, bh1, Wh2, bh2,
                                        p_ws, valid_ws, hv_ws);
    mpnn_interf<<<(KN*DEG)/256, 256, 0, stream>>>(edge_idx, p_ws, valid_ws,
                                                  hv_ws, out);
}

// Round 8
// 29.929 us; speedup vs baseline: 1.1778x; 1.1778x over previous
//
#include <hip/hip_runtime.h>
#include <hip/hip_bf16.h>
#include <math.h>

#define KN 8192
#define DEG 32
#define EE (KN*DEG)

// VAR = float32(10^(-19.9) * 5000000 / 10)
#define VAR_F 6.294627058970831e-15f

typedef __attribute__((ext_vector_type(8)))  short bf16x8;
typedef __attribute__((ext_vector_type(16))) float f32x16;

static __device__ __forceinline__ short bf_hi(float f) {
    __hip_bfloat16 h = __float2bfloat16(f);
    return __builtin_bit_cast(short, h);
}
static __device__ __forceinline__ float bf_f(short s) {
    __hip_bfloat16 h = __builtin_bit_cast(__hip_bfloat16, s);
    return __bfloat162float(h);
}

// Kernel 1: fused 3x conv + head + H-row gather. ONE wave per block/node.
// All weight loads are flat lane-linear (fully coalesced 256B transactions,
// no replication); reduction trees absorb the layout via extra shuffles.
// Weights register-resident across the 3 convs. msg GEMM via
// mfma_f32_32x32x16_bf16, 3-term hi/lo split (~fp32 precision).
// Wave-private LDS only -> no barriers.
__global__ __launch_bounds__(64, 4) void mpnn_fused(
    const float* __restrict__ x,
    const float* __restrict__ edge_attr,
    const float* __restrict__ H,
    const int* __restrict__ edge_index,
    const float* __restrict__ Wm1, const float* __restrict__ bm1,
    const float* __restrict__ Wm2, const float* __restrict__ bm2,
    const float* __restrict__ Wu1, const float* __restrict__ bu1,
    const float* __restrict__ Wu2, const float* __restrict__ bu2,
    const float* __restrict__ Wh1, const float* __restrict__ bh1,
    const float* __restrict__ Wh2, const float* __restrict__ bh2,
    float* __restrict__ p_ws, float* __restrict__ valid_ws,
    float* __restrict__ hv_ws)
{
    __shared__ __align__(16) float c_lds[32];
    __shared__ float xt[44];    // [0..8]=x, [9..40]=aggr
    __shared__ float ubuf[16];

    const int lane = threadIdx.x;
    const int col  = lane & 31;
    const int g    = lane >> 5;
    const int k    = blockIdx.x;

    const int m  = lane & 15;
    const int dg = lane >> 4;        // 0..3
    const int o  = lane & 7;
    const int mg = lane >> 3;        // 0..7

    // ---- H-row gather first (longest dependent chain: dst -> H line) ----
    const int* dstp = edge_index + EE;
    const int dv = dstp[k*DEG + col];
    const float Hv    = H[(size_t)k*KN + dv];       // random 4B within row
    const float Hdiag = H[(size_t)k*KN + k];        // uniform -> 1 line

    // ================= flat coalesced weight loads =================
    const float a_e = edge_attr[k*32 + col];          // edge e = col

    // Wm1 flat: element 64t+lane -> (d = 2t+g, j = col). t=4,g=1 is row d=9.
    float wm1v[5];
    #pragma unroll
    for (int t = 0; t < 5; ++t) wm1v[t] = Wm1[(size_t)k*320 + t*64 + lane];

    // Wm1 row 9 in A-fragment order: j = s*16 + g*8 + i
    float w9v[16];
    {
        const float* w9p = Wm1 + (size_t)k*320 + 288;
        float4 wa = *(const float4*)(w9p + g*8);
        float4 wb = *(const float4*)(w9p + g*8 + 4);
        float4 wc = *(const float4*)(w9p + 16 + g*8);
        float4 wd = *(const float4*)(w9p + 16 + g*8 + 4);
        w9v[0]=wa.x;  w9v[1]=wa.y;  w9v[2]=wa.z;  w9v[3]=wa.w;
        w9v[4]=wb.x;  w9v[5]=wb.y;  w9v[6]=wb.z;  w9v[7]=wb.w;
        w9v[8]=wc.x;  w9v[9]=wc.y;  w9v[10]=wc.z; w9v[11]=wc.w;
        w9v[12]=wd.x; w9v[13]=wd.y; w9v[14]=wd.z; w9v[15]=wd.w;
    }

    // Wm2 in B-fragment order (2 coalesced 128B rows per instr)
    float wm2f[16];
    #pragma unroll
    for (int s = 0; s < 2; ++s)
        #pragma unroll
        for (int i = 0; i < 8; ++i)
            wm2f[s*8+i] = Wm2[(size_t)k*1024 + (s*16 + g*8 + i)*32 + col];

    const float bm1_i = bm1[k*32 + col];
    const float bm2_i = bm2[k*32 + col];

    // Wu1 flat: element 64t+lane -> (d = 4t+dg, m = lane&15), t=0..9; tail d=40.
    float wu1v[10];
    #pragma unroll
    for (int t = 0; t < 10; ++t) wu1v[t] = Wu1[(size_t)k*656 + t*64 + lane];
    float wu1t = 0.f;
    if (lane < 16) wu1t = Wu1[(size_t)k*656 + 640 + lane];
    const float bu1_m = bu1[k*16 + m];

    const float wu2a  = Wu2[(size_t)k*128 + (mg*2+0)*8 + o];
    const float wu2b  = Wu2[(size_t)k*128 + (mg*2+1)*8 + o];
    const float bu2_o = bu2[k*8 + o];

    // Wh1 flat: element 64t+lane -> (d = 4t+dg, m = lane&15), t=0..1.
    float wh1v[2];
    #pragma unroll
    for (int t = 0; t < 2; ++t) wh1v[t] = Wh1[(size_t)k*128 + t*64 + lane];
    const float bh1_m = bh1[k*16 + m];
    const float wh2_m = Wh2[k*16 + m];
    const float bh2_k = bh2[k];

    if (lane < 9) xt[lane] = x[(size_t)k*9 + lane];

    // stash gathered H values immediately (frees reg, overlaps store)
    if (g == 0) hv_ws[k*DEG + col] = Hv;
    if (lane == 0) valid_ws[KN + k] = Hdiag;   // staging slot for Hdiag

    // ================= conversions (after loads issued) =================
    bf16x8 Bhi[2], Blo[2];
    #pragma unroll
    for (int s = 0; s < 2; ++s) {
        #pragma unroll
        for (int i = 0; i < 8; ++i) {
            float wv = wm2f[s*8+i];
            short h = bf_hi(wv);
            Bhi[s][i] = h;
            Blo[s][i] = bf_hi(wv - bf_f(h));
        }
    }

    // ================= 3x conv =================
    for (int it = 0; it < 3; ++it) {
        // c_j = bm1_j + sum_{d<9} x_d Wm1[d][j]; lane holds d = 2t+g, j=col.
        // t=4,g=1 is row 9 (excluded from c).
        float cpart = 0.f;
        #pragma unroll
        for (int t = 0; t < 4; ++t) cpart = fmaf(xt[2*t + g], wm1v[t], cpart);
        if (g == 0) cpart = fmaf(xt[8], wm1v[4], cpart);
        float c = bm1_i + cpart + __shfl_xor(cpart, 32);
        if (g == 0) c_lds[col] = c;

        // A frags: A[e=col][kk=s*16+g*8+i] = relu(c_j + a_e*Wm1[9][j])
        const float4* cb = (const float4*)c_lds;
        float4 q0 = cb[g*2 + 0];
        float4 q1 = cb[g*2 + 1];
        float4 q2 = cb[4 + g*2 + 0];
        float4 q3 = cb[4 + g*2 + 1];
        float cv[16] = {q0.x,q0.y,q0.z,q0.w, q1.x,q1.y,q1.z,q1.w,
                        q2.x,q2.y,q2.z,q2.w, q3.x,q3.y,q3.z,q3.w};
        bf16x8 Ahi[2], Alo[2];
        #pragma unroll
        for (int s = 0; s < 2; ++s) {
            #pragma unroll
            for (int i = 0; i < 8; ++i) {
                int t = s*8 + i;
                float hv = fmaxf(fmaf(a_e, w9v[t], cv[t]), 0.f);
                short h = bf_hi(hv);
                Ahi[s][i] = h;
                Alo[s][i] = bf_hi(hv - bf_f(h));
            }
        }

        // msg GEMM: D[e][i] = sum_j h[e][j] Wm2[j][i]
        f32x16 acc;
        #pragma unroll
        for (int rr = 0; rr < 16; ++rr) acc[rr] = 0.f;
        #pragma unroll
        for (int s = 0; s < 2; ++s) {
            acc = __builtin_amdgcn_mfma_f32_32x32x16_bf16(Ahi[s], Bhi[s], acc, 0, 0, 0);
            acc = __builtin_amdgcn_mfma_f32_32x32x16_bf16(Ahi[s], Blo[s], acc, 0, 0, 0);
            acc = __builtin_amdgcn_mfma_f32_32x32x16_bf16(Alo[s], Bhi[s], acc, 0, 0, 0);
        }

        // aggr_i = sum_e relu(bm2_i + D[e][i])
        float ag = 0.f;
        #pragma unroll
        for (int rr = 0; rr < 16; ++rr) ag += fmaxf(acc[rr] + bm2_i, 0.f);
        ag += __shfl_xor(ag, 32);
        if (g == 0) xt[9 + col] = ag;

        // u_m = relu(bu1_m + sum_{d<41} t_d Wu1[d][m]); lane holds d = 4t+dg.
        float up = 0.f;
        #pragma unroll
        for (int t = 0; t < 10; ++t) up = fmaf(xt[4*t + dg], wu1v[t], up);
        up = fmaf(xt[40], wu1t, up);             // wu1t==0 for lane>=16
        up += __shfl_xor(up, 16);
        up += __shfl_xor(up, 32);
        float u = fmaxf(up + bu1_m, 0.f);
        if (lane < 16) ubuf[lane] = u;

        // comb_o = relu(bu2_o + sum_m u_m Wu2[m][o])
        float cp = wu2a * ubuf[mg*2] + wu2b * ubuf[mg*2 + 1];
        cp += __shfl_xor(cp, 8);
        cp += __shfl_xor(cp, 16);
        cp += __shfl_xor(cp, 32);
        float comb = fmaxf(cp + bu2_o, 0.f);
        if (lane < 8) xt[1 + lane] = comb;   // x_new = [x0, comb]
    }

    // ================= head =================
    // hh_m = relu(bh1_m + sum_{d<8} emb_d Wh1[d][m]); lane holds d = 4t+dg.
    float hp = fmaf(xt[1 + dg], wh1v[0], 0.f);
    hp = fmaf(xt[1 + 4 + dg], wh1v[1], hp);
    hp += __shfl_xor(hp, 16);
    hp += __shfl_xor(hp, 32);
    float hh = fmaxf(hp + bh1_m, 0.f);
    float pp = hh * wh2_m;
    pp += __shfl_xor(pp, 1);
    pp += __shfl_xor(pp, 2);
    pp += __shfl_xor(pp, 4);
    pp += __shfl_xor(pp, 8);
    float z = pp + bh2_k;
    float p = 1.f / (1.f + expf(-z));
    if (lane == 0) {
        p_ws[k] = p;
        valid_ws[k] = p * Hdiag;
    }
}

// Kernel 2b: interference reduce from compact buffers, vectorized.
// 8 lanes per node, 4 edges per lane via int4/float4; 32 nodes per block.
__global__ __launch_bounds__(256) void mpnn_interf(
    const int* __restrict__ edge_index,
    const float* __restrict__ p_ws,
    const float* __restrict__ valid_ws,
    const float* __restrict__ hv_ws,
    float* __restrict__ out)
{
    const int tid = threadIdx.x;
    const int s   = blockIdx.x * 32 + (tid >> 3);
    const int e4  = tid & 7;
    const int* dstp = edge_index + EE;

    int4   d4 = ((const int4*)  (dstp  + s*DEG))[e4];
    float4 h4 = ((const float4*)(hv_ws + s*DEG))[e4];
    float part = p_ws[d4.x] * h4.x + p_ws[d4.y] * h4.y
               + p_ws[d4.z] * h4.z + p_ws[d4.w] * h4.w;
    part += __shfl_xor(part, 1);
    part += __shfl_xor(part, 2);
    part += __shfl_xor(part, 4);
    if (e4 == 0) {
        float interf = part + VAR_F;
        out[s] = -log1pf(valid_ws[s] / interf) * 1.4426950408889634f;
    }
}

extern "C" void kernel_launch(void* const* d_in, const int* in_sizes, int n_in,
                              void* d_out, int out_size, void* d_ws, size_t ws_size,
                              hipStream_t stream) {
    const float* x         = (const float*)d_in[0];
    const float* edge_attr = (const float*)d_in[1];
    const float* H         = (const float*)d_in[2];
    const int*   edge_idx  = (const int*)  d_in[3];
    const float* Wm1 = (const float*)d_in[4];
    const float* bm1 = (const float*)d_in[5];
    const float* Wm2 = (const float*)d_in[6];
    const float* bm2 = (const float*)d_in[7];
    const float* Wu1 = (const float*)d_in[8];
    const float* bu1 = (const float*)d_in[9];
    const float* Wu2 = (const float*)d_in[10];
    const float* bu2 = (const float*)d_in[11];
    const float* Wh1 = (const float*)d_in[12];
    const float* bh1 = (const float*)d_in[13];
    const float* Wh2 = (const float*)d_in[14];
    const float* bh2 = (const float*)d_in[15];
    float* out = (float*)d_out;

    float* p_ws     = (float*)d_ws;            // KN
    float* valid_ws = p_ws + KN;               // 2*KN (valid + Hdiag staging)
    float* hv_ws    = valid_ws + 2*KN;         // KN*DEG

    mpnn_fused<<<KN, 64, 0, stream>>>(x, edge_attr, H, edge_idx,
                                      Wm1, bm1, Wm2, bm2,
                                      Wu1, bu1, Wu2, bu2, Wh1, bh1, Wh2, bh2,
                                      p_ws, valid_ws, hv_ws);
    mpnn_interf<<<KN/32, 256, 0, stream>>>(edge_idx, p_ws, valid_ws,
                                           hv_ws, out);
}